// Round 2
// 507.289 us; speedup vs baseline: 1.0977x; 1.0977x over previous
//
#include <hip/hip_runtime.h>

// Problem constants (fixed by the reference)
#define T_TOK 4096   // B*S tokens
#define DIM   1024   // model dim D
#define HID   1024   // expert hidden H
#define NEXP  16     // routed experts
#define HSH   2048   // shared hidden = NSH*H
#define NIN   2      // experts that consume x instead of emb
#define MT_MAX 80    // max routed m-tiles: (8192 + 16*127)/128 rounded up

typedef __attribute__((ext_vector_type(8))) short bf8_t;  // 8 x bf16 (MFMA A/B frag)
typedef __attribute__((ext_vector_type(4))) float f4_t;   // 4 x f32  (MFMA C/D frag)

__device__ __forceinline__ ushort f2b(float f) {  // f32 -> bf16 RNE
  unsigned u = __float_as_uint(f);
  u = (u + 0x7FFFu + ((u >> 16) & 1u)) >> 16;
  return (ushort)u;
}

// ---------------------------------------------------------------------------
// Tile-packed (TP) layout: matrix [NR][NK] stored as 128x64 tiles, row-major
// tile grid (KT = NK/64 tiles per tile-row), 8192 elems (16KB) per tile,
// contiguous. Element (r,c) at r*64 + XOR-swizzled column (by r&7) so MFMA
// fragment ds_read_b128 are bank-conflict-free. DMA copies tiles verbatim.
// ---------------------------------------------------------------------------
__device__ __forceinline__ int tp_off(int r, int c) {
  return r * 64 + ((((c >> 3) ^ (r & 7)) << 3) | (c & 7));
}
__device__ __forceinline__ size_t tp_idx(int row, int col, int KT) {
  return ((size_t)((row >> 7) * KT + (col >> 6)) << 13) + tp_off(row & 127, col & 63);
}

// Async global->LDS DMA, 16B/lane; LDS dest is wave-uniform base + lane*16.
__device__ __forceinline__ void gl_lds16(const ushort* g, ushort* l) {
  __builtin_amdgcn_global_load_lds(
      (const __attribute__((address_space(1))) void*)g,
      (__attribute__((address_space(3))) void*)l, 16, 0, 0);
}

// ---------------------------------------------------------------------------
// TP MFMA K-loop: nkt tiles of K=64. Each wave DMA-stages a contiguous 4KB
// quarter of each 16KB tile. 4 waves: 64x64 C-quadrants via 16x16x32 MFMA.
// ---------------------------------------------------------------------------
template<bool DUAL>
__device__ __forceinline__ void mfma_tp(
    const ushort* __restrict__ aT, const ushort* __restrict__ b1T,
    const ushort* __restrict__ b3T, int nkt,
    ushort* As, ushort* Bs1, ushort* Bs3,
    f4_t acc1[4][4], f4_t acc3[4][4], int tid)
{
  const int lane = tid & 63, w = tid >> 6;
  const int wm = w & 1, wn = w >> 1;
  const int quad = lane >> 4, lr = lane & 15;
  const int soff = w << 11;          // wave's 2048-elem quarter
  const int l8 = lane * 8;

  for (int kt = 0; kt < nkt; kt++) {
    const size_t tb = (size_t)kt << 13;
    const ushort* ga = aT + tb + soff + l8;
    const ushort* gb = b1T + tb + soff + l8;
    #pragma unroll
    for (int d = 0; d < 4; d++) {
      gl_lds16(ga + (d << 9), As  + soff + (d << 9));
      gl_lds16(gb + (d << 9), Bs1 + soff + (d << 9));
    }
    if (DUAL) {
      const ushort* gc = b3T + tb + soff + l8;
      #pragma unroll
      for (int d = 0; d < 4; d++)
        gl_lds16(gc + (d << 9), Bs3 + soff + (d << 9));
    }
    __syncthreads();
    #pragma unroll
    for (int half = 0; half < 2; half++) {
      const int ch = (half << 2) + quad;   // k-chunk index 0..7
      bf8_t af[4];
      #pragma unroll
      for (int mi = 0; mi < 4; mi++) {
        const int r = wm * 64 + mi * 16 + lr;
        af[mi] = *(const bf8_t*)&As[r * 64 + ((ch ^ (r & 7)) << 3)];
      }
      #pragma unroll
      for (int ni = 0; ni < 4; ni++) {
        const int n = wn * 64 + ni * 16 + lr;
        bf8_t b1 = *(const bf8_t*)&Bs1[n * 64 + ((ch ^ (n & 7)) << 3)];
        #pragma unroll
        for (int mi = 0; mi < 4; mi++)
          acc1[mi][ni] = __builtin_amdgcn_mfma_f32_16x16x32_bf16(af[mi], b1, acc1[mi][ni], 0, 0, 0);
        if (DUAL) {
          bf8_t b3 = *(const bf8_t*)&Bs3[n * 64 + ((ch ^ (n & 7)) << 3)];
          #pragma unroll
          for (int mi = 0; mi < 4; mi++)
            acc3[mi][ni] = __builtin_amdgcn_mfma_f32_16x16x32_bf16(af[mi], b3, acc3[mi][ni], 0, 0, 0);
        }
      }
    }
    __syncthreads();
  }
}

// ---------------------------------------------------------------------------
// ONE-CHUNK band transpose+cast+TP-pack: src fp32 [R][C], band = 64 k-rows,
// chunk = 256 n-cols. Phase A: full-wave contiguous 1KB row reads -> bf16
// LDS [64][264] (pad 8). Phase B: 4n x 8k register micro-transpose from
// conflict-free ds reads, 16B TP stores. No internal chunk loop: each block
// does exactly one chunk so blocks overlap each other's phases on the CU.
// ---------------------------------------------------------------------------
__device__ __forceinline__ void tr_chunk(const float* __restrict__ src,
                                         ushort* __restrict__ dst,
                                         int R, int C, int band, int c, int tid,
                                         ushort* ts)
{
  const int KT = R >> 6;
  const int k0 = band * 64;
  // Phase A: 64 rows x 256 cols fp32 -> bf16 LDS. Wave = one 1KB row chunk.
  #pragma unroll
  for (int i = 0; i < 16; i++) {
    const int idx = i * 256 + tid;          // 0..4095
    const int r = idx >> 6, c4 = idx & 63;  // row, float4-col
    const float4 v = *(const float4*)(src + (size_t)(k0 + r) * C + c * 256 + c4 * 4);
    ushort4 u;
    u.x = f2b(v.x); u.y = f2b(v.y); u.z = f2b(v.z); u.w = f2b(v.w);
    *(ushort4*)&ts[r * 264 + c4 * 4] = u;
  }
  __syncthreads();
  // Phase B: micro-transpose, 2 steps x (4n x 8k) per thread.
  #pragma unroll
  for (int s = 0; s < 2; s++) {
    const int m = s * 256 + tid;            // 0..511
    const int ng = m & 63, kc = m >> 6;     // n-group (4 n), k-chunk 0..7
    ushort vv[32];
    #pragma unroll
    for (int j = 0; j < 8; j++)
      *(ushort4*)&vv[j * 4] = *(const ushort4*)&ts[(kc * 8 + j) * 264 + ng * 4];
    #pragma unroll
    for (int i = 0; i < 4; i++) {
      ushort o[8];
      #pragma unroll
      for (int j = 0; j < 8; j++) o[j] = vv[j * 4 + i];
      const int n = c * 256 + ng * 4 + i;
      *(uint4*)&dst[tp_idx(n, k0 + kc * 8, KT)] = *(uint4*)o;
    }
  }
}

// ---------------------------------------------------------------------------
// MEGA-PREP flat dispatch (heavy transpose blocks FIRST):
//   [0,3072)        W1/W3/W2: 48 slices x 16 bands x 4 chunks
//   [3072,3200)     sW1 (R=1024,C=2048): 16 bands x 8 chunks
//   [3200,3328)     sW2 (R=2048,C=1024): 32 bands x 4 chunks
//   [3328,4352)     gate: wave-parallel softmax+top2, 1 wave = 1 token
//   [4352,4864)     cast emb->etp, x->xtp (TP only; no flat copies)
// ---------------------------------------------------------------------------
#define PREP_BLOCKS 4864
__launch_bounds__(256, 4)
__global__ void prep(const float* __restrict__ emb, const float* __restrict__ x_,
                     const float* __restrict__ gw,
                     const float* __restrict__ W1, const float* __restrict__ W3,
                     const float* __restrict__ W2,
                     const float* __restrict__ sW1, const float* __restrict__ sW2,
                     ushort* __restrict__ etp, ushort* __restrict__ xtp,
                     ushort* __restrict__ w1tp, ushort* __restrict__ w3tp,
                     ushort* __restrict__ w2tp,
                     ushort* __restrict__ sw1tp, ushort* __restrict__ sw2tp,
                     int* __restrict__ eA, int* __restrict__ eB,
                     float* __restrict__ wA, float* __restrict__ wB)
{
  __shared__ ushort ts[64 * 264];   // 33792 B (transpose blocks only)
  const int b = blockIdx.x;
  const int t = threadIdx.x;

  if (b < 3328) {
    // ---------------- weight transposes, one chunk per block ----------------
    const float* src; ushort* dst; int R, C, band, chunk;
    if (b < 3072) {
      const int z = b >> 6, rem = b & 63;        // slice 0..47
      band = rem >> 2; chunk = rem & 3;
      const int e = z & 15;
      src = ((z < 16) ? W1 : (z < 32) ? W3 : W2) + ((size_t)e << 20);
      dst = ((z < 16) ? w1tp : (z < 32) ? w3tp : w2tp) + ((size_t)e << 20);
      R = 1024; C = 1024;
    } else if (b < 3200) {
      const int i = b - 3072; band = i >> 3; chunk = i & 7;
      src = sW1; dst = sw1tp; R = 1024; C = 2048;
    } else {
      const int i = b - 3200; band = i >> 2; chunk = i & 3;
      src = sW2; dst = sw2tp; R = 2048; C = 1024;
    }
    tr_chunk(src, dst, R, C, band, chunk, t, ts);
  } else if (b < 4352) {
    // ---------------- gate: 1 wave per token, fully parallel ----------------
    const int w = t >> 6, lane = t & 63;
    const int tok = (b - 3328) * 4 + w;
    const int e = lane & 15, q = lane >> 4;      // expert, k-quarter
    const float* er = emb + (size_t)tok * DIM + q * 256;
    const float* gr = gw + (size_t)e * DIM + q * 256;
    float p = 0.f;
    #pragma unroll 8
    for (int j = 0; j < 64; j++) {
      const float4 a = *(const float4*)(er + j * 4);
      const float4 g = *(const float4*)(gr + j * 4);
      p += a.x * g.x + a.y * g.y + a.z * g.z + a.w * g.w;
    }
    p += __shfl_xor(p, 16); p += __shfl_xor(p, 32);   // full dot, replicated x4
    float m1 = p;
    m1 = fmaxf(m1, __shfl_xor(m1, 1)); m1 = fmaxf(m1, __shfl_xor(m1, 2));
    m1 = fmaxf(m1, __shfl_xor(m1, 4)); m1 = fmaxf(m1, __shfl_xor(m1, 8));
    float sum = __expf(p - m1);
    sum += __shfl_xor(sum, 1); sum += __shfl_xor(sum, 2);
    sum += __shfl_xor(sum, 4); sum += __shfl_xor(sum, 8);
    const int i0 = __ffsll(__ballot(p == m1) & 0xFFFFull) - 1;
    const float p2 = (e == i0) ? -3.402823466e38f : p;
    float m2 = p2;
    m2 = fmaxf(m2, __shfl_xor(m2, 1)); m2 = fmaxf(m2, __shfl_xor(m2, 2));
    m2 = fmaxf(m2, __shfl_xor(m2, 4)); m2 = fmaxf(m2, __shfl_xor(m2, 8));
    const int i1 = __ffsll(__ballot(p2 == m2) & 0xFFFFull) - 1;
    if (lane == 0) {
      const float inv = 1.0f / sum;
      eA[tok] = i0; wA[tok] = inv;                    // exp(m1-m1) == 1
      eB[tok] = i1; wB[tok] = __expf(m2 - m1) * inv;
    }
  } else {
    // ---------------- cast emb/x -> TP bf16 ----------------
    const int NC = (T_TOK * DIM) / 8;               // 8-elem chunks per tensor
    const int c0 = (b - 4352) * 256 + t;            // 131072 threads
    for (int c = c0; c < 2 * NC; c += 512 * 256) {
      const bool isE = c < NC;
      const int g = (isE ? c : c - NC) << 3;
      const float* src = isE ? emb : x_;
      const float4 v0 = *(const float4*)(src + g);
      const float4 v1 = *(const float4*)(src + g + 4);
      ushort tt[8];
      tt[0] = f2b(v0.x); tt[1] = f2b(v0.y); tt[2] = f2b(v0.z); tt[3] = f2b(v0.w);
      tt[4] = f2b(v1.x); tt[5] = f2b(v1.y); tt[6] = f2b(v1.z); tt[7] = f2b(v1.w);
      const int row = g >> 10, col = g & 1023;
      ushort* dst = isE ? etp : xtp;
      *(uint4*)&dst[tp_idx(row, col, 16)] = *(uint4*)tt;
    }
  }
}

// ---------------------------------------------------------------------------
// Build per-expert compact lists from per-token top-2 (deterministic, no
// global atomics): one block per expert, ballot prefix over 16 rounds.
// ---------------------------------------------------------------------------
__global__ void build_lists(const int* __restrict__ eA, const int* __restrict__ eB,
                            const float* __restrict__ wA, const float* __restrict__ wB,
                            int* __restrict__ cnt, int* __restrict__ list,
                            float* __restrict__ wl)
{
  const int e = blockIdx.x;
  __shared__ int wsum[4];
  __shared__ int sbase;
  const int tid = threadIdx.x;
  const int lane = tid & 63, wv = tid >> 6;
  if (tid == 0) sbase = 0;
  __syncthreads();
  for (int r = 0; r < 16; r++) {
    const int tk = r * 256 + tid;
    const int a = eA[tk], bb = eB[tk];
    const bool m = (a == e) || (bb == e);
    const float w = (a == e) ? wA[tk] : wB[tk];
    const unsigned long long bal = __ballot(m);
    const int pw = __popcll(bal & ((1ULL << lane) - 1ULL));
    if (lane == 63) wsum[wv] = pw + (m ? 1 : 0);
    __syncthreads();
    int base = sbase;
    for (int k = 0; k < wv; k++) base += wsum[k];
    if (m) {
      const int pos = base + pw;
      list[e * T_TOK + pos] = tk;
      wl[e * T_TOK + pos] = w;
    }
    __syncthreads();
    if (tid == 0) sbase += wsum[0] + wsum[1] + wsum[2] + wsum[3];
    __syncthreads();
  }
  if (tid == 0) cnt[e] = sbase;
}

// offp[e] = 128-aligned prefix sum; offp[17] = #m-tiles; tbl[2*mt] = {e, row0}
__global__ void scan_offs(const int* __restrict__ cnt, int* __restrict__ offp,
                          int* __restrict__ tbl)
{
  if (blockIdx.x == 0 && threadIdx.x == 0) {
    int a = 0, nm = 0;
    for (int e = 0; e < NEXP; e++) {
      offp[e] = a;
      const int c = (cnt[e] + 127) & ~127;
      for (int r = 0; r < c; r += 128) { tbl[2 * nm] = e; tbl[2 * nm + 1] = a + r; nm++; }
      a += c;
    }
    offp[NEXP] = a;
    offp[NEXP + 1] = nm;
  }
}

// ---------------------------------------------------------------------------
// Gather routed A rows into TP compact form (pad slots -> zeros). Grid
// MT_MAX x 8: mt = b>>3, 128-col slice = b&7. Sources are TP now: a token
// row's 16B chunk is contiguous in TP, so reads stay vectorized.
// ---------------------------------------------------------------------------
__global__ void gather_a(const ushort* __restrict__ etp, const ushort* __restrict__ xtp,
                         const int* __restrict__ cnt, const int* __restrict__ offp,
                         const int* __restrict__ tbl, const int* __restrict__ list,
                         ushort* __restrict__ ag)
{
  const int mt = blockIdx.x >> 3;
  if (mt >= offp[NEXP + 1]) return;
  const int sl = blockIdx.x & 7;
  const int e = tbl[2 * mt], row0 = tbl[2 * mt + 1];
  const int ce = cnt[e];
  const int s0 = row0 - offp[e];
  const ushort* src = (e < NIN) ? xtp : etp;
  const int tid = threadIdx.x;
  #pragma unroll
  for (int rep = 0; rep < 8; rep++) {
    const int lin = rep * 256 + tid;        // 128 rows x 16 chunks
    const int r = lin >> 4, c8 = (sl * 128) + ((lin & 15) << 3);
    const int s = s0 + r;
    uint4 v = make_uint4(0u, 0u, 0u, 0u);
    if (s < ce) {
      const int tok = list[e * T_TOK + s];
      v = *(const uint4*)&src[tp_idx(tok, c8, 16)];
    }
    *(uint4*)&ag[tp_idx(row0 + r, c8, 16)] = v;
  }
}

// ---------------------------------------------------------------------------
// Stage 1, flat grid: b < 512 -> shared front (hs TP); else routed SwiGLU
// front (h TP), table-driven m-tiles. 48KB LDS x 3 blocks/CU.
// ---------------------------------------------------------------------------
__launch_bounds__(256, 3)
__global__ void stage1(const ushort* __restrict__ ag, const ushort* __restrict__ etp,
                       const ushort* __restrict__ w1tp, const ushort* __restrict__ w3tp,
                       const ushort* __restrict__ sw1tp,
                       const float* __restrict__ B1, const float* __restrict__ B3,
                       const float* __restrict__ sB1,
                       const int* __restrict__ offp, const int* __restrict__ tbl,
                       ushort* __restrict__ h_tp, ushort* __restrict__ hs_tp)
{
  __shared__ ushort As[8192], Bs1[8192], Bs3[8192];
  const int tid = threadIdx.x;
  const int lane = tid & 63, w = tid >> 6;
  const int wm = w & 1, wn = w >> 1;
  const int quad = lane >> 4, lr = lane & 15;
  const int b = blockIdx.x;

  f4_t acc1[4][4], acc3[4][4];
  const f4_t fz = {0.f, 0.f, 0.f, 0.f};
  #pragma unroll
  for (int i = 0; i < 4; i++)
    #pragma unroll
    for (int j = 0; j < 4; j++) { acc1[i][j] = fz; acc3[i][j] = fz; }

  if (b < 512) {                       // ---- shared expert front: all real
    const int m0 = (b >> 4) << 7;
    const int n0 = (b & 15) << 7;
    const ushort* aT = etp + ((size_t)((m0 >> 7) * 16) << 13);
    const ushort* bT = sw1tp + ((size_t)((n0 >> 7) * 16) << 13);
    mfma_tp<false>(aT, bT, nullptr, 16, As, Bs1, Bs3, acc1, acc3, tid);
    #pragma unroll
    for (int mi = 0; mi < 4; mi++) {
      #pragma unroll
      for (int r = 0; r < 4; r++) {
        const int row = m0 + wm * 64 + mi * 16 + quad * 4 + r;
        #pragma unroll
        for (int ni = 0; ni < 4; ni++) {
          const int col = n0 + wn * 64 + ni * 16 + lr;
          const float v = acc1[mi][ni][r] + sB1[col];
          const float sg = 1.0f / (1.0f + __expf(-v));
          hs_tp[tp_idx(row, col, 32)] = f2b(v * sg);
        }
      }
    }
  } else {                             // ---- routed SwiGLU front
    const int t = b - 512;
    const int mt = t >> 3;
    if (mt >= offp[NEXP + 1]) return;
    const int n0 = (t & 7) << 7;
    const int e = tbl[2 * mt], row0 = tbl[2 * mt + 1];
    const ushort* aT  = ag + ((size_t)((row0 >> 7) * 16) << 13);
    const ushort* b1T = w1tp + ((size_t)e << 20) + ((size_t)((n0 >> 7) * 16) << 13);
    const ushort* b3T = w3tp + ((size_t)e << 20) + ((size_t)((n0 >> 7) * 16) << 13);
    mfma_tp<true>(aT, b1T, b3T, 16, As, Bs1, Bs3, acc1, acc3, tid);
    #pragma unroll
    for (int mi = 0; mi < 4; mi++) {
      #pragma unroll
      for (int r = 0; r < 4; r++) {
        const int grow = row0 + wm * 64 + mi * 16 + quad * 4 + r;
        #pragma unroll
        for (int ni = 0; ni < 4; ni++) {
          const int col = n0 + wn * 64 + ni * 16 + lr;
          const float v1 = acc1[mi][ni][r] + B1[e * HID + col];
          const float v3 = acc3[mi][ni][r] + B3[e * HID + col];
          const float sg = 1.0f / (1.0f + __expf(-v1));
          h_tp[tp_idx(grow, col, 16)] = f2b(v1 * sg * v3);
        }
      }
    }
  }
}

// ---------------------------------------------------------------------------
// Stage 2, flat grid: b < 256 -> shared back; else routed back (table-driven).
// Both atomicAdd into zero-inited y. 32KB LDS x 4 blocks/CU.
// ---------------------------------------------------------------------------
__launch_bounds__(256, 4)
__global__ void stage2(const ushort* __restrict__ h_tp, const ushort* __restrict__ hs_tp,
                       const ushort* __restrict__ w2tp, const ushort* __restrict__ sw2tp,
                       const float* __restrict__ B2, const float* __restrict__ sB2,
                       const int* __restrict__ cnt, const int* __restrict__ offp,
                       const int* __restrict__ tbl, const int* __restrict__ list,
                       const float* __restrict__ wl, float* __restrict__ y)
{
  __shared__ ushort As[8192], Bs[8192];
  const int tid = threadIdx.x;
  const int lane = tid & 63, w = tid >> 6;
  const int wm = w & 1, wn = w >> 1;
  const int quad = lane >> 4, lr = lane & 15;
  const int b = blockIdx.x;

  f4_t acc[4][4];
  const f4_t fz = {0.f, 0.f, 0.f, 0.f};
  #pragma unroll
  for (int i = 0; i < 4; i++)
    #pragma unroll
    for (int j = 0; j < 4; j++) acc[i][j] = fz;

  if (b < 256) {                       // ---- shared expert back (K=2048)
    const int m0 = (b >> 3) << 7;
    const int n0 = (b & 7) << 7;
    const ushort* aT = hs_tp + ((size_t)((m0 >> 7) * 32) << 13);
    const ushort* bT = sw2tp + ((size_t)((n0 >> 7) * 32) << 13);
    mfma_tp<false>(aT, bT, nullptr, 32, As, Bs, Bs, acc, acc, tid);
    #pragma unroll
    for (int mi = 0; mi < 4; mi++) {
      #pragma unroll
      for (int r = 0; r < 4; r++) {
        const int row = m0 + wm * 64 + mi * 16 + quad * 4 + r;
        float* yr = y + (size_t)row * DIM;
        #pragma unroll
        for (int ni = 0; ni < 4; ni++) {
          const int col = n0 + wn * 64 + ni * 16 + lr;
          atomicAdd(&yr[col], acc[mi][ni][r] + sB2[col]);
        }
      }
    }
  } else {                             // ---- routed back (K=1024)
    const int t = b - 256;
    const int mt = t >> 3;
    if (mt >= offp[NEXP + 1]) return;
    const int n0 = (t & 7) << 7;
    const int e = tbl[2 * mt], row0 = tbl[2 * mt + 1];
    const int ce = cnt[e];
    const int s0 = row0 - offp[e];
    const ushort* aT = h_tp + ((size_t)((row0 >> 7) * 16) << 13);
    const ushort* bT = w2tp + ((size_t)e << 20) + ((size_t)((n0 >> 7) * 16) << 13);
    mfma_tp<false>(aT, bT, nullptr, 16, As, Bs, Bs, acc, acc, tid);
    #pragma unroll
    for (int mi = 0; mi < 4; mi++) {
      #pragma unroll
      for (int r = 0; r < 4; r++) {
        const int rowl = s0 + wm * 64 + mi * 16 + quad * 4 + r;
        if (rowl < ce) {
          const int tok = list[e * T_TOK + rowl];
          const float wgt = wl[e * T_TOK + rowl];
          float* yr = y + (size_t)tok * DIM;
          #pragma unroll
          for (int ni = 0; ni < 4; ni++) {
            const int col = n0 + wn * 64 + ni * 16 + lr;
            atomicAdd(&yr[col], wgt * (acc[mi][ni][r] + B2[e * DIM + col]));
          }
        }
      }
    }
  }
}

// ---------------------------------------------------------------------------
// Launch
// ---------------------------------------------------------------------------
extern "C" void kernel_launch(void* const* d_in, const int* in_sizes, int n_in,
                              void* d_out, int out_size, void* d_ws, size_t ws_size,
                              hipStream_t stream)
{
  const float* emb = (const float*)d_in[0];
  const float* x   = (const float*)d_in[1];
  const float* gw  = (const float*)d_in[2];
  const float* W1  = (const float*)d_in[3];
  const float* B1  = (const float*)d_in[4];
  const float* W2  = (const float*)d_in[5];
  const float* B2  = (const float*)d_in[6];
  const float* W3  = (const float*)d_in[7];
  const float* B3  = (const float*)d_in[8];
  const float* sW1 = (const float*)d_in[9];
  const float* sB1 = (const float*)d_in[10];
  const float* sW2 = (const float*)d_in[11];
  const float* sB2 = (const float*)d_in[12];
  float* y = (float*)d_out;

  char* ws = (char*)d_ws;
  const size_t MB = 1024ULL * 1024ULL;
  ushort* xtp   = (ushort*)(ws + 0);        // x TP (KT=16)
  ushort* etp   = (ushort*)(ws + 16 * MB);  // emb TP (KT=16)
  ushort* w1tp  = (ushort*)(ws + 24 * MB);  // [16] x TP [1024n][1024k]
  ushort* w3tp  = (ushort*)(ws + 56 * MB);
  ushort* w2tp  = (ushort*)(ws + 88 * MB);  // [16] x TP [1024n][1024k]
  ushort* sw1tp = (ushort*)(ws + 120 * MB); // TP [2048n][1024k]
  ushort* sw2tp = (ushort*)(ws + 124 * MB); // TP [1024n][2048k]
  ushort* ag    = (ushort*)(ws + 128 * MB); // gathered A, TP, <=10240 rows
  ushort* h_tp  = (ushort*)(ws + 148 * MB); // routed hidden, TP, <=10240 rows
  ushort* hs_tp = (ushort*)(ws + 168 * MB); // shared hidden, TP [4096][2048]
  int*   cnt    = (int*)(ws + 184 * MB);    // [16]
  int*   offp   = cnt + 16;                 // [18]  (offp[17] = #m-tiles)
  int*   tbl    = offp + 18;                // [2*MT_MAX]
  int*   list   = (int*)(ws + 184 * MB + 1024);            // [16][4096]
  float* wl     = (float*)(ws + 184 * MB + 1024 + 262144); // [16][4096]
  int*   eA     = (int*)(ws + 185 * MB);    // [4096]
  int*   eB     = eA + T_TOK;
  float* wA     = (float*)(eB + T_TOK);
  float* wB     = wA + T_TOK;

  hipMemsetAsync(y, 0, (size_t)T_TOK * DIM * sizeof(float), stream);
  prep<<<PREP_BLOCKS, 256, 0, stream>>>(emb, x, gw, W1, W3, W2, sW1, sW2,
                                        etp, xtp, w1tp, w3tp, w2tp,
                                        sw1tp, sw2tp, eA, eB, wA, wB);
  build_lists<<<NEXP, 256, 0, stream>>>(eA, eB, wA, wB, cnt, list, wl);
  scan_offs<<<1, 64, 0, stream>>>(cnt, offp, tbl);
  gather_a<<<MT_MAX * 8, 256, 0, stream>>>(etp, xtp, cnt, offp, tbl, list, ag);
  stage1<<<512 + MT_MAX * 8, 256, 0, stream>>>(ag, etp, w1tp, w3tp, sw1tp,
                                               B1, B3, sB1, offp, tbl, h_tp, hs_tp);
  stage2<<<256 + MT_MAX * 8, 256, 0, stream>>>(h_tp, hs_tp, w2tp, sw2tp, B2, sB2,
                                               cnt, offp, tbl, list, wl, y);
}

// Round 4
// 485.323 us; speedup vs baseline: 1.1474x; 1.0453x over previous
//
#include <hip/hip_runtime.h>

// Problem constants (fixed by the reference)
#define T_TOK 4096   // B*S tokens
#define DIM   1024   // model dim D
#define HID   1024   // expert hidden H
#define NEXP  16     // routed experts
#define HSH   2048   // shared hidden = NSH*H
#define NIN   2      // experts that consume x instead of emb
#define MT_MAX 80    // max routed m-tiles: (8192 + 16*127)/128 rounded up

typedef __attribute__((ext_vector_type(8))) short bf8_t;  // 8 x bf16 (MFMA A/B frag)
typedef __attribute__((ext_vector_type(4))) float f4_t;   // 4 x f32  (MFMA C/D frag)

__device__ __forceinline__ ushort f2b(float f) {  // f32 -> bf16 RNE
  unsigned u = __float_as_uint(f);
  u = (u + 0x7FFFu + ((u >> 16) & 1u)) >> 16;
  return (ushort)u;
}

// ---------------------------------------------------------------------------
// Tile-packed (TP) layout: matrix [NR][NK] stored as 128x64 tiles, row-major
// tile grid (KT = NK/64 tiles per tile-row), 8192 elems (16KB) per tile,
// contiguous. Element (r,c) at r*64 + XOR-swizzled column (by r&7) so MFMA
// fragment ds_read_b128 are bank-conflict-free. DMA copies tiles verbatim.
// ---------------------------------------------------------------------------
__device__ __forceinline__ int tp_off(int r, int c) {
  return r * 64 + ((((c >> 3) ^ (r & 7)) << 3) | (c & 7));
}
__device__ __forceinline__ size_t tp_idx(int row, int col, int KT) {
  return ((size_t)((row >> 7) * KT + (col >> 6)) << 13) + tp_off(row & 127, col & 63);
}

// Async global->LDS DMA, 16B/lane; LDS dest is wave-uniform base + lane*16.
__device__ __forceinline__ void gl_lds16(const ushort* g, ushort* l) {
  __builtin_amdgcn_global_load_lds(
      (const __attribute__((address_space(1))) void*)g,
      (__attribute__((address_space(3))) void*)l, 16, 0, 0);
}

// ---------------------------------------------------------------------------
// TP MFMA K-loop: nkt tiles of K=64. Each wave DMA-stages a contiguous 4KB
// quarter of each 16KB tile. 4 waves: 64x64 C-quadrants via 16x16x32 MFMA.
// ---------------------------------------------------------------------------
template<bool DUAL>
__device__ __forceinline__ void mfma_tp(
    const ushort* __restrict__ aT, const ushort* __restrict__ b1T,
    const ushort* __restrict__ b3T, int nkt,
    ushort* As, ushort* Bs1, ushort* Bs3,
    f4_t acc1[4][4], f4_t acc3[4][4], int tid)
{
  const int lane = tid & 63, w = tid >> 6;
  const int wm = w & 1, wn = w >> 1;
  const int quad = lane >> 4, lr = lane & 15;
  const int soff = w << 11;          // wave's 2048-elem quarter
  const int l8 = lane * 8;

  for (int kt = 0; kt < nkt; kt++) {
    const size_t tb = (size_t)kt << 13;
    const ushort* ga = aT + tb + soff + l8;
    const ushort* gb = b1T + tb + soff + l8;
    #pragma unroll
    for (int d = 0; d < 4; d++) {
      gl_lds16(ga + (d << 9), As  + soff + (d << 9));
      gl_lds16(gb + (d << 9), Bs1 + soff + (d << 9));
    }
    if (DUAL) {
      const ushort* gc = b3T + tb + soff + l8;
      #pragma unroll
      for (int d = 0; d < 4; d++)
        gl_lds16(gc + (d << 9), Bs3 + soff + (d << 9));
    }
    __syncthreads();
    #pragma unroll
    for (int half = 0; half < 2; half++) {
      const int ch = (half << 2) + quad;   // k-chunk index 0..7
      bf8_t af[4];
      #pragma unroll
      for (int mi = 0; mi < 4; mi++) {
        const int r = wm * 64 + mi * 16 + lr;
        af[mi] = *(const bf8_t*)&As[r * 64 + ((ch ^ (r & 7)) << 3)];
      }
      #pragma unroll
      for (int ni = 0; ni < 4; ni++) {
        const int n = wn * 64 + ni * 16 + lr;
        bf8_t b1 = *(const bf8_t*)&Bs1[n * 64 + ((ch ^ (n & 7)) << 3)];
        #pragma unroll
        for (int mi = 0; mi < 4; mi++)
          acc1[mi][ni] = __builtin_amdgcn_mfma_f32_16x16x32_bf16(af[mi], b1, acc1[mi][ni], 0, 0, 0);
        if (DUAL) {
          bf8_t b3 = *(const bf8_t*)&Bs3[n * 64 + ((ch ^ (n & 7)) << 3)];
          #pragma unroll
          for (int mi = 0; mi < 4; mi++)
            acc3[mi][ni] = __builtin_amdgcn_mfma_f32_16x16x32_bf16(af[mi], b3, acc3[mi][ni], 0, 0, 0);
        }
      }
    }
    __syncthreads();
  }
}

// ---------------------------------------------------------------------------
// ONE-CHUNK band transpose+cast+TP-pack: src fp32 [R][C], band = 64 k-rows,
// chunk = 256 n-cols.
// Phase A: full-wave contiguous 1KB row reads -> bf16 LDS [64][264] with 8B
// chunks XOR-swizzled by (r>>3)&7 (so Phase B gathers are <=2-way conflicts).
// Phase B: thread = (n, kc): gather 8 k-values (scalar u16 LDS reads) for one
// 16B TP chunk. Wave lanes map n = base+(l>>3), kc = l&7 -> the wave's 64
// stores cover an 8-row x 64-col = 1KB CONTIGUOUS TP region (fully coalesced;
// the TP XOR swizzle only permutes 16B chunks inside it).
// ---------------------------------------------------------------------------
__device__ __forceinline__ void tr_chunk(const float* __restrict__ src,
                                         ushort* __restrict__ dst,
                                         int R, int C, int band, int c, int tid,
                                         ushort* ts)
{
  const int KT = R >> 6;
  const int k0 = band * 64;
  // Phase A: 64 rows x 256 cols fp32 -> bf16 LDS. Wave = one 1KB row chunk.
  #pragma unroll
  for (int i = 0; i < 16; i++) {
    const int idx = i * 256 + tid;          // 0..4095
    const int r = idx >> 6, c4 = idx & 63;  // row, float4-col
    const float4 v = *(const float4*)(src + (size_t)(k0 + r) * C + c * 256 + c4 * 4);
    ushort4 u;
    u.x = f2b(v.x); u.y = f2b(v.y); u.z = f2b(v.z); u.w = f2b(v.w);
    *(ushort4*)&ts[r * 264 + ((c4 ^ ((r >> 3) & 7)) << 2)] = u;
  }
  __syncthreads();
  // Phase B: 8 steps; each thread emits one 16B TP chunk per step.
  #pragma unroll
  for (int s = 0; s < 8; s++) {
    const int idx = s * 256 + tid;          // 0..2047 = 256 n x 8 kc
    const int n = idx >> 3, kc = idx & 7;
    ushort o[8];
    #pragma unroll
    for (int j = 0; j < 8; j++)
      o[j] = ts[(kc * 8 + j) * 264 + (((n >> 2) ^ kc) << 2) + (n & 3)];
    *(uint4*)&dst[tp_idx(c * 256 + n, k0 + kc * 8, KT)] = *(uint4*)o;
  }
}

// ---------------------------------------------------------------------------
// MEGA-PREP flat dispatch (heavy transpose blocks FIRST):
//   [0,3072)        W1/W3/W2: 48 slices x 16 bands x 4 chunks
//   [3072,3200)     sW1 (R=1024,C=2048): 16 bands x 8 chunks
//   [3200,3328)     sW2 (R=2048,C=1024): 32 bands x 4 chunks
//   [3328,4352)     gate: wave-parallel softmax+top2, 1 wave = 1 token
//   [4352,4864)     cast emb->etp, x->xtp (TP only; no flat copies)
// ---------------------------------------------------------------------------
#define PREP_BLOCKS 4864
__launch_bounds__(256, 4)
__global__ void prep(const float* __restrict__ emb, const float* __restrict__ x_,
                     const float* __restrict__ gw,
                     const float* __restrict__ W1, const float* __restrict__ W3,
                     const float* __restrict__ W2,
                     const float* __restrict__ sW1, const float* __restrict__ sW2,
                     ushort* __restrict__ etp, ushort* __restrict__ xtp,
                     ushort* __restrict__ w1tp, ushort* __restrict__ w3tp,
                     ushort* __restrict__ w2tp,
                     ushort* __restrict__ sw1tp, ushort* __restrict__ sw2tp,
                     int* __restrict__ eA, int* __restrict__ eB,
                     float* __restrict__ wA, float* __restrict__ wB)
{
  __shared__ ushort ts[64 * 264];   // 33792 B (transpose blocks only)
  const int b = blockIdx.x;
  const int t = threadIdx.x;

  if (b < 3328) {
    // ---------------- weight transposes, one chunk per block ----------------
    const float* src; ushort* dst; int R, C, band, chunk;
    if (b < 3072) {
      const int z = b >> 6, rem = b & 63;        // slice 0..47
      band = rem >> 2; chunk = rem & 3;
      const int e = z & 15;
      src = ((z < 16) ? W1 : (z < 32) ? W3 : W2) + ((size_t)e << 20);
      dst = ((z < 16) ? w1tp : (z < 32) ? w3tp : w2tp) + ((size_t)e << 20);
      R = 1024; C = 1024;
    } else if (b < 3200) {
      const int i = b - 3072; band = i >> 3; chunk = i & 7;
      src = sW1; dst = sw1tp; R = 1024; C = 2048;
    } else {
      const int i = b - 3200; band = i >> 2; chunk = i & 3;
      src = sW2; dst = sw2tp; R = 2048; C = 1024;
    }
    tr_chunk(src, dst, R, C, band, chunk, t, ts);
  } else if (b < 4352) {
    // ---- gate: 1 wave = 1 token; all loads 1KB-contiguous per instruction.
    // Lane owns 4-float slices at lane*4 + jj*256; full 64-lane butterfly
    // reduce gives every lane all 16 scores; lane 0 writes top-2.
    const int w = t >> 6, lane = t & 63;
    const int tok = (b - 3328) * 4 + w;
    const float* er = emb + (size_t)tok * DIM + lane * 4;
    const float4 a0 = *(const float4*)(er);
    const float4 a1 = *(const float4*)(er + 256);
    const float4 a2 = *(const float4*)(er + 512);
    const float4 a3 = *(const float4*)(er + 768);
    float pe[NEXP];
    #pragma unroll
    for (int e = 0; e < NEXP; e++) {
      const float* gr = gw + (size_t)e * DIM + lane * 4;
      const float4 g0 = *(const float4*)(gr);
      const float4 g1 = *(const float4*)(gr + 256);
      const float4 g2 = *(const float4*)(gr + 512);
      const float4 g3 = *(const float4*)(gr + 768);
      float p = a0.x * g0.x + a0.y * g0.y + a0.z * g0.z + a0.w * g0.w;
      p += a1.x * g1.x + a1.y * g1.y + a1.z * g1.z + a1.w * g1.w;
      p += a2.x * g2.x + a2.y * g2.y + a2.z * g2.z + a2.w * g2.w;
      p += a3.x * g3.x + a3.y * g3.y + a3.z * g3.z + a3.w * g3.w;
      pe[e] = p;
    }
    #pragma unroll
    for (int e = 0; e < NEXP; e++) {
      float v = pe[e];
      v += __shfl_xor(v, 1);  v += __shfl_xor(v, 2);
      v += __shfl_xor(v, 4);  v += __shfl_xor(v, 8);
      v += __shfl_xor(v, 16); v += __shfl_xor(v, 32);
      pe[e] = v;
    }
    if (lane == 0) {
      float m1 = pe[0];
      #pragma unroll
      for (int j = 1; j < NEXP; j++) m1 = fmaxf(m1, pe[j]);
      float sum = 0.f;
      #pragma unroll
      for (int j = 0; j < NEXP; j++) sum += __expf(pe[j] - m1);
      int i0 = 0; float b0 = pe[0];
      #pragma unroll
      for (int j = 1; j < NEXP; j++) if (pe[j] > b0) { b0 = pe[j]; i0 = j; }
      int i1 = -1; float b1 = -3.402823466e38f;
      #pragma unroll
      for (int j = 0; j < NEXP; j++) if (j != i0 && pe[j] > b1) { b1 = pe[j]; i1 = j; }
      const float inv = 1.0f / sum;
      eA[tok] = i0; wA[tok] = __expf(b0 - m1) * inv;   // b0 == m1 -> inv
      eB[tok] = i1; wB[tok] = __expf(b1 - m1) * inv;
    }
  } else {
    // ---------------- cast emb/x -> TP bf16 ----------------
    const int NC = (T_TOK * DIM) / 8;               // 8-elem chunks per tensor
    const int c0 = (b - 4352) * 256 + t;            // 131072 threads
    for (int c = c0; c < 2 * NC; c += 512 * 256) {
      const bool isE = c < NC;
      const int g = (isE ? c : c - NC) << 3;
      const float* src = isE ? emb : x_;
      const float4 v0 = *(const float4*)(src + g);
      const float4 v1 = *(const float4*)(src + g + 4);
      ushort tt[8];
      tt[0] = f2b(v0.x); tt[1] = f2b(v0.y); tt[2] = f2b(v0.z); tt[3] = f2b(v0.w);
      tt[4] = f2b(v1.x); tt[5] = f2b(v1.y); tt[6] = f2b(v1.z); tt[7] = f2b(v1.w);
      const int row = g >> 10, col = g & 1023;
      ushort* dst = isE ? etp : xtp;
      *(uint4*)&dst[tp_idx(row, col, 16)] = *(uint4*)tt;
    }
  }
}

// ---------------------------------------------------------------------------
// Build per-expert compact lists from per-token top-2 (deterministic, no
// global atomics): one block per expert, ballot prefix over 16 rounds.
// ---------------------------------------------------------------------------
__global__ void build_lists(const int* __restrict__ eA, const int* __restrict__ eB,
                            const float* __restrict__ wA, const float* __restrict__ wB,
                            int* __restrict__ cnt, int* __restrict__ list,
                            float* __restrict__ wl)
{
  const int e = blockIdx.x;
  __shared__ int wsum[4];
  __shared__ int sbase;
  const int tid = threadIdx.x;
  const int lane = tid & 63, wv = tid >> 6;
  if (tid == 0) sbase = 0;
  __syncthreads();
  for (int r = 0; r < 16; r++) {
    const int tk = r * 256 + tid;
    const int a = eA[tk], bb = eB[tk];
    const bool m = (a == e) || (bb == e);
    const float w = (a == e) ? wA[tk] : wB[tk];
    const unsigned long long bal = __ballot(m);
    const int pw = __popcll(bal & ((1ULL << lane) - 1ULL));
    if (lane == 63) wsum[wv] = pw + (m ? 1 : 0);
    __syncthreads();
    int base = sbase;
    for (int k = 0; k < wv; k++) base += wsum[k];
    if (m) {
      const int pos = base + pw;
      list[e * T_TOK + pos] = tk;
      wl[e * T_TOK + pos] = w;
    }
    __syncthreads();
    if (tid == 0) sbase += wsum[0] + wsum[1] + wsum[2] + wsum[3];
    __syncthreads();
  }
  if (tid == 0) cnt[e] = sbase;
}

// offp[e] = 128-aligned prefix sum; offp[17] = #m-tiles; tbl[2*mt] = {e, row0}
__global__ void scan_offs(const int* __restrict__ cnt, int* __restrict__ offp,
                          int* __restrict__ tbl)
{
  if (blockIdx.x == 0 && threadIdx.x == 0) {
    int a = 0, nm = 0;
    for (int e = 0; e < NEXP; e++) {
      offp[e] = a;
      const int c = (cnt[e] + 127) & ~127;
      for (int r = 0; r < c; r += 128) { tbl[2 * nm] = e; tbl[2 * nm + 1] = a + r; nm++; }
      a += c;
    }
    offp[NEXP] = a;
    offp[NEXP + 1] = nm;
  }
}

// ---------------------------------------------------------------------------
// Gather routed A rows into TP compact form (pad slots -> zeros). Grid
// MT_MAX x 8: mt = b>>3, 128-col slice = b&7. Sources are TP: a token row's
// 16B chunk is contiguous in TP, so reads stay vectorized.
// ---------------------------------------------------------------------------
__global__ void gather_a(const ushort* __restrict__ etp, const ushort* __restrict__ xtp,
                         const int* __restrict__ cnt, const int* __restrict__ offp,
                         const int* __restrict__ tbl, const int* __restrict__ list,
                         ushort* __restrict__ ag)
{
  const int mt = blockIdx.x >> 3;
  if (mt >= offp[NEXP + 1]) return;
  const int sl = blockIdx.x & 7;
  const int e = tbl[2 * mt], row0 = tbl[2 * mt + 1];
  const int ce = cnt[e];
  const int s0 = row0 - offp[e];
  const ushort* src = (e < NIN) ? xtp : etp;
  const int tid = threadIdx.x;
  #pragma unroll
  for (int rep = 0; rep < 8; rep++) {
    const int lin = rep * 256 + tid;        // 128 rows x 16 chunks
    const int r = lin >> 4, c8 = (sl * 128) + ((lin & 15) << 3);
    const int s = s0 + r;
    uint4 v = make_uint4(0u, 0u, 0u, 0u);
    if (s < ce) {
      const int tok = list[e * T_TOK + s];
      v = *(const uint4*)&src[tp_idx(tok, c8, 16)];
    }
    *(uint4*)&ag[tp_idx(row0 + r, c8, 16)] = v;
  }
}

// ---------------------------------------------------------------------------
// Stage 1, flat grid: b < 512 -> shared front (hs TP); else routed SwiGLU
// front (h TP), table-driven m-tiles. 48KB LDS x 3 blocks/CU.
// ---------------------------------------------------------------------------
__launch_bounds__(256, 3)
__global__ void stage1(const ushort* __restrict__ ag, const ushort* __restrict__ etp,
                       const ushort* __restrict__ w1tp, const ushort* __restrict__ w3tp,
                       const ushort* __restrict__ sw1tp,
                       const float* __restrict__ B1, const float* __restrict__ B3,
                       const float* __restrict__ sB1,
                       const int* __restrict__ offp, const int* __restrict__ tbl,
                       ushort* __restrict__ h_tp, ushort* __restrict__ hs_tp)
{
  __shared__ ushort As[8192], Bs1[8192], Bs3[8192];
  const int tid = threadIdx.x;
  const int lane = tid & 63, w = tid >> 6;
  const int wm = w & 1, wn = w >> 1;
  const int quad = lane >> 4, lr = lane & 15;
  const int b = blockIdx.x;

  f4_t acc1[4][4], acc3[4][4];
  const f4_t fz = {0.f, 0.f, 0.f, 0.f};
  #pragma unroll
  for (int i = 0; i < 4; i++)
    #pragma unroll
    for (int j = 0; j < 4; j++) { acc1[i][j] = fz; acc3[i][j] = fz; }

  if (b < 512) {                       // ---- shared expert front: all real
    const int m0 = (b >> 4) << 7;
    const int n0 = (b & 15) << 7;
    const ushort* aT = etp + ((size_t)((m0 >> 7) * 16) << 13);
    const ushort* bT = sw1tp + ((size_t)((n0 >> 7) * 16) << 13);
    mfma_tp<false>(aT, bT, nullptr, 16, As, Bs1, Bs3, acc1, acc3, tid);
    #pragma unroll
    for (int mi = 0; mi < 4; mi++) {
      #pragma unroll
      for (int r = 0; r < 4; r++) {
        const int row = m0 + wm * 64 + mi * 16 + quad * 4 + r;
        #pragma unroll
        for (int ni = 0; ni < 4; ni++) {
          const int col = n0 + wn * 64 + ni * 16 + lr;
          const float v = acc1[mi][ni][r] + sB1[col];
          const float sg = 1.0f / (1.0f + __expf(-v));
          hs_tp[tp_idx(row, col, 32)] = f2b(v * sg);
        }
      }
    }
  } else {                             // ---- routed SwiGLU front
    const int t = b - 512;
    const int mt = t >> 3;
    if (mt >= offp[NEXP + 1]) return;
    const int n0 = (t & 7) << 7;
    const int e = tbl[2 * mt], row0 = tbl[2 * mt + 1];
    const ushort* aT  = ag + ((size_t)((row0 >> 7) * 16) << 13);
    const ushort* b1T = w1tp + ((size_t)e << 20) + ((size_t)((n0 >> 7) * 16) << 13);
    const ushort* b3T = w3tp + ((size_t)e << 20) + ((size_t)((n0 >> 7) * 16) << 13);
    mfma_tp<true>(aT, b1T, b3T, 16, As, Bs1, Bs3, acc1, acc3, tid);
    #pragma unroll
    for (int mi = 0; mi < 4; mi++) {
      #pragma unroll
      for (int r = 0; r < 4; r++) {
        const int grow = row0 + wm * 64 + mi * 16 + quad * 4 + r;
        #pragma unroll
        for (int ni = 0; ni < 4; ni++) {
          const int col = n0 + wn * 64 + ni * 16 + lr;
          const float v1 = acc1[mi][ni][r] + B1[e * HID + col];
          const float v3 = acc3[mi][ni][r] + B3[e * HID + col];
          const float sg = 1.0f / (1.0f + __expf(-v1));
          h_tp[tp_idx(grow, col, 16)] = f2b(v1 * sg * v3);
        }
      }
    }
  }
}

// ---------------------------------------------------------------------------
// Stage 2, flat grid: b < 256 -> shared back; else routed back (table-driven).
// Both atomicAdd into zero-inited y. 32KB LDS x 4 blocks/CU.
// ---------------------------------------------------------------------------
__launch_bounds__(256, 4)
__global__ void stage2(const ushort* __restrict__ h_tp, const ushort* __restrict__ hs_tp,
                       const ushort* __restrict__ w2tp, const ushort* __restrict__ sw2tp,
                       const float* __restrict__ B2, const float* __restrict__ sB2,
                       const int* __restrict__ cnt, const int* __restrict__ offp,
                       const int* __restrict__ tbl, const int* __restrict__ list,
                       const float* __restrict__ wl, float* __restrict__ y)
{
  __shared__ ushort As[8192], Bs[8192];
  const int tid = threadIdx.x;
  const int lane = tid & 63, w = tid >> 6;
  const int wm = w & 1, wn = w >> 1;
  const int quad = lane >> 4, lr = lane & 15;
  const int b = blockIdx.x;

  f4_t acc[4][4];
  const f4_t fz = {0.f, 0.f, 0.f, 0.f};
  #pragma unroll
  for (int i = 0; i < 4; i++)
    #pragma unroll
    for (int j = 0; j < 4; j++) acc[i][j] = fz;

  if (b < 256) {                       // ---- shared expert back (K=2048)
    const int m0 = (b >> 3) << 7;
    const int n0 = (b & 7) << 7;
    const ushort* aT = hs_tp + ((size_t)((m0 >> 7) * 32) << 13);
    const ushort* bT = sw2tp + ((size_t)((n0 >> 7) * 32) << 13);
    mfma_tp<false>(aT, bT, nullptr, 32, As, Bs, Bs, acc, acc, tid);
    #pragma unroll
    for (int mi = 0; mi < 4; mi++) {
      #pragma unroll
      for (int r = 0; r < 4; r++) {
        const int row = m0 + wm * 64 + mi * 16 + quad * 4 + r;
        float* yr = y + (size_t)row * DIM;
        #pragma unroll
        for (int ni = 0; ni < 4; ni++) {
          const int col = n0 + wn * 64 + ni * 16 + lr;
          atomicAdd(&yr[col], acc[mi][ni][r] + sB2[col]);
        }
      }
    }
  } else {                             // ---- routed back (K=1024)
    const int t = b - 256;
    const int mt = t >> 3;
    if (mt >= offp[NEXP + 1]) return;
    const int n0 = (t & 7) << 7;
    const int e = tbl[2 * mt], row0 = tbl[2 * mt + 1];
    const int ce = cnt[e];
    const int s0 = row0 - offp[e];
    const ushort* aT = h_tp + ((size_t)((row0 >> 7) * 16) << 13);
    const ushort* bT = w2tp + ((size_t)e << 20) + ((size_t)((n0 >> 7) * 16) << 13);
    mfma_tp<false>(aT, bT, nullptr, 16, As, Bs, Bs, acc, acc, tid);
    #pragma unroll
    for (int mi = 0; mi < 4; mi++) {
      #pragma unroll
      for (int r = 0; r < 4; r++) {
        const int rowl = s0 + wm * 64 + mi * 16 + quad * 4 + r;
        if (rowl < ce) {
          const int tok = list[e * T_TOK + rowl];
          const float wgt = wl[e * T_TOK + rowl];
          float* yr = y + (size_t)tok * DIM;
          #pragma unroll
          for (int ni = 0; ni < 4; ni++) {
            const int col = n0 + wn * 64 + ni * 16 + lr;
            atomicAdd(&yr[col], wgt * (acc[mi][ni][r] + B2[e * DIM + col]));
          }
        }
      }
    }
  }
}

// ---------------------------------------------------------------------------
// Launch
// ---------------------------------------------------------------------------
extern "C" void kernel_launch(void* const* d_in, const int* in_sizes, int n_in,
                              void* d_out, int out_size, void* d_ws, size_t ws_size,
                              hipStream_t stream)
{
  const float* emb = (const float*)d_in[0];
  const float* x   = (const float*)d_in[1];
  const float* gw  = (const float*)d_in[2];
  const float* W1  = (const float*)d_in[3];
  const float* B1  = (const float*)d_in[4];
  const float* W2  = (const float*)d_in[5];
  const float* B2  = (const float*)d_in[6];
  const float* W3  = (const float*)d_in[7];
  const float* B3  = (const float*)d_in[8];
  const float* sW1 = (const float*)d_in[9];
  const float* sB1 = (const float*)d_in[10];
  const float* sW2 = (const float*)d_in[11];
  const float* sB2 = (const float*)d_in[12];
  float* y = (float*)d_out;

  char* ws = (char*)d_ws;
  const size_t MB = 1024ULL * 1024ULL;
  ushort* xtp   = (ushort*)(ws + 0);        // x TP (KT=16)
  ushort* etp   = (ushort*)(ws + 16 * MB);  // emb TP (KT=16)
  ushort* w1tp  = (ushort*)(ws + 24 * MB);  // [16] x TP [1024n][1024k]
  ushort* w3tp  = (ushort*)(ws + 56 * MB);
  ushort* w2tp  = (ushort*)(ws + 88 * MB);  // [16] x TP [1024n][1024k]
  ushort* sw1tp = (ushort*)(ws + 120 * MB); // TP [2048n][1024k]
  ushort* sw2tp = (ushort*)(ws + 124 * MB); // TP [1024n][2048k]
  ushort* ag    = (ushort*)(ws + 128 * MB); // gathered A, TP, <=10240 rows
  ushort* h_tp  = (ushort*)(ws + 148 * MB); // routed hidden, TP, <=10240 rows
  ushort* hs_tp = (ushort*)(ws + 168 * MB); // shared hidden, TP [4096][2048]
  int*   cnt    = (int*)(ws + 184 * MB);    // [16]
  int*   offp   = cnt + 16;                 // [18]  (offp[17] = #m-tiles)
  int*   tbl    = offp + 18;                // [2*MT_MAX]
  int*   list   = (int*)(ws + 184 * MB + 1024);            // [16][4096]
  float* wl     = (float*)(ws + 184 * MB + 1024 + 262144); // [16][4096]
  int*   eA     = (int*)(ws + 185 * MB);    // [4096]
  int*   eB     = eA + T_TOK;
  float* wA     = (float*)(eB + T_TOK);
  float* wB     = wA + T_TOK;

  hipMemsetAsync(y, 0, (size_t)T_TOK * DIM * sizeof(float), stream);
  prep<<<PREP_BLOCKS, 256, 0, stream>>>(emb, x, gw, W1, W3, W2, sW1, sW2,
                                        etp, xtp, w1tp, w3tp, w2tp,
                                        sw1tp, sw2tp, eA, eB, wA, wB);
  build_lists<<<NEXP, 256, 0, stream>>>(eA, eB, wA, wB, cnt, list, wl);
  scan_offs<<<1, 64, 0, stream>>>(cnt, offp, tbl);
  gather_a<<<MT_MAX * 8, 256, 0, stream>>>(etp, xtp, cnt, offp, tbl, list, ag);
  stage1<<<512 + MT_MAX * 8, 256, 0, stream>>>(ag, etp, w1tp, w3tp, sw1tp,
                                               B1, B3, sB1, offp, tbl, h_tp, hs_tp);
  stage2<<<256 + MT_MAX * 8, 256, 0, stream>>>(h_tp, hs_tp, w2tp, sw2tp, B2, sB2,
                                               cnt, offp, tbl, list, wl, y);
}